// Round 12
// baseline (252.771 us; speedup 1.0000x reference)
//
#include <hip/hip_runtime.h>
#include <hip/hip_bf16.h>
#include <stdint.h>

typedef __bf16 bf16;
typedef __bf16 bf16x8 __attribute__((ext_vector_type(8)));
typedef float  f32x4  __attribute__((ext_vector_type(4)));

static constexpr int S_LEN = 2048;
static constexpr int HIDN  = 2048;
static constexpr int BATCH = 2;
static constexpr int MTOT  = BATCH * S_LEN;   // 4096
static constexpr int NH    = 8;
static constexpr int DH    = 256;
static constexpr int NPAD  = 2688;            // 2612 proj cols padded to 21*128
static constexpr float QSCALE = 0.0625f / 6.0f;  // SCALING(1/16) * 1/RQ

__device__ __forceinline__ void gload16(const bf16* g, const bf16* l) {
  __builtin_amdgcn_global_load_lds(
      (const __attribute__((address_space(1))) void*)g,
      (__attribute__((address_space(3))) void*)l, 16, 0, 0);
}

// ---------------------------------------------------------------- casts
__global__ void cast_x_kernel(const float* __restrict__ in, bf16* __restrict__ out) {
  int i = blockIdx.x * blockDim.x + threadIdx.x;          // one thread per 8 elems
  const float4* p = reinterpret_cast<const float4*>(in) + 2 * (size_t)i;
  float4 a = p[0], b = p[1];
  bf16x8 o;
  o[0]=(bf16)a.x; o[1]=(bf16)a.y; o[2]=(bf16)a.z; o[3]=(bf16)a.w;
  o[4]=(bf16)b.x; o[5]=(bf16)b.y; o[6]=(bf16)b.z; o[7]=(bf16)b.w;
  reinterpret_cast<bf16x8*>(out)[i] = o;
}

__global__ void cast_w_kernel(const float* __restrict__ Wq, const float* __restrict__ Wk,
                              const float* __restrict__ Wv, const float* __restrict__ Bq,
                              const float* __restrict__ Bk, const float* __restrict__ Bv,
                              const float* __restrict__ Wo, bf16* __restrict__ Wcat,
                              bf16* __restrict__ Wob) {
  int row = blockIdx.x;
  int c = threadIdx.x * 8;
  const float* src = nullptr;
  bf16* dst;
  if (row < NPAD) {
    dst = Wcat + (size_t)row * HIDN;
    if      (row <   48) src = Wq + (size_t)row        * HIDN;
    else if (row <   50) src = Wk + (size_t)(row-  48) * HIDN;
    else if (row <   52) src = Wv + (size_t)(row-  50) * HIDN;
    else if (row < 1588) src = Bq + (size_t)(row-  52) * HIDN;
    else if (row < 2100) src = Bk + (size_t)(row-1588) * HIDN;
    else if (row < 2612) src = Bv + (size_t)(row-2100) * HIDN;
  } else {
    dst = Wob + (size_t)(row - NPAD) * HIDN;
    src = Wo + (size_t)(row - NPAD) * HIDN;
  }
  bf16x8 o;
  if (src) {
    const float4* p = reinterpret_cast<const float4*>(src + c);
    float4 a = p[0], b = p[1];
    o[0]=(bf16)a.x; o[1]=(bf16)a.y; o[2]=(bf16)a.z; o[3]=(bf16)a.w;
    o[4]=(bf16)b.x; o[5]=(bf16)b.y; o[6]=(bf16)b.z; o[7]=(bf16)b.w;
  } else {
    #pragma unroll
    for (int j = 0; j < 8; ++j) o[j] = (bf16)0.f;
  }
  *reinterpret_cast<bf16x8*>(dst + c) = o;
}

// ---------------------------------------------------------------- GEMM (B^T input)
// 256x128 tile, BK=64, 8 waves (4M x 2N, each wave 64x64 = 16 frags).
// T3 2-phase dbuf + rule-#21 both-sides swizzle + XCD swizzle.
// 256 MFMA per barrier (2x the 128^2 tile) -- barrier amortization.
template <typename OutT>
__launch_bounds__(512)
__global__ void gemm_bt_kernel(const bf16* __restrict__ A, const bf16* __restrict__ Bt,
                               OutT* __restrict__ C, int K, int N) {
  __shared__ __align__(16) bf16 As[2][256 * 64];   // 64 KB
  __shared__ __align__(16) bf16 Bs[2][128 * 64];   // 32 KB
  const int t = threadIdx.x;
  const int lane = t & 63, wid = t >> 6;
  const int g = lane >> 4, c16 = lane & 15;
  const int nwg = (int)(gridDim.x * gridDim.y);
  int flat = (int)(blockIdx.y * gridDim.x + blockIdx.x);
  flat = (flat & 7) * (nwg >> 3) + (flat >> 3);            // XCD swizzle (nwg % 8 == 0)
  const int bxs = flat % (int)gridDim.x, bys = flat / (int)gridDim.x;
  const int rowA0 = bys * 256, rowB0 = bxs * 128;
  const int wm = wid >> 1, wn = wid & 1;                  // 4M x 2N wave grid
  const int wrow = wm * 64, wcol = wn * 64;
  const int srow = (lane >> 3), sunit = lane & 7;         // staging: 8 rows x 8 units
  const int sgx = (sunit ^ (srow & 7)) * 8;               // inverse-swizzled global col
  const int rswz = c16 & 7;                               // read-side swizzle key
  f32x4 z = {0.f, 0.f, 0.f, 0.f};
  f32x4 acc[4][4];
  #pragma unroll
  for (int m = 0; m < 4; ++m)
    #pragma unroll
    for (int n = 0; n < 4; ++n) acc[m][n] = z;

  auto stage = [&](int buf, int kt) {
    #pragma unroll
    for (int i = 0; i < 4; ++i) {                 // A: wave stages rows [wid*32, +32)
      int r0 = wid * 32 + i * 8;
      gload16(A + (size_t)(rowA0 + r0 + srow) * K + kt + sgx, &As[buf][r0 * 64]);
    }
    #pragma unroll
    for (int i = 0; i < 2; ++i) {                 // B: wave stages rows [wid*16, +16)
      int r0 = wid * 16 + i * 8;
      gload16(Bt + (size_t)(rowB0 + r0 + srow) * K + kt + sgx, &Bs[buf][r0 * 64]);
    }
  };

  const int nk = K >> 6;
  stage(0, 0);
  __syncthreads();
  for (int ti = 0; ti < nk; ++ti) {
    const int cb = ti & 1;
    if (ti + 1 < nk) stage(cb ^ 1, (ti + 1) * 64);       // prefetch next K-tile
    #pragma unroll
    for (int ks = 0; ks < 2; ++ks) {
      bf16x8 af[4], bfr[4];
      #pragma unroll
      for (int m = 0; m < 4; ++m)
        af[m] = *reinterpret_cast<const bf16x8*>(
            &As[cb][(wrow + m*16 + c16) * 64 + ((ks*4 + g) ^ rswz) * 8]);
      #pragma unroll
      for (int n = 0; n < 4; ++n)
        bfr[n] = *reinterpret_cast<const bf16x8*>(
            &Bs[cb][(wcol + n*16 + c16) * 64 + ((ks*4 + g) ^ rswz) * 8]);
      __builtin_amdgcn_s_setprio(1);
      #pragma unroll
      for (int m = 0; m < 4; ++m)
        #pragma unroll
        for (int n = 0; n < 4; ++n)
          acc[m][n] = __builtin_amdgcn_mfma_f32_16x16x32_bf16(af[m], bfr[n], acc[m][n], 0, 0, 0);
      __builtin_amdgcn_s_setprio(0);
    }
    __syncthreads();                                     // drains prefetch (landed under MFMA)
  }
  #pragma unroll
  for (int m = 0; m < 4; ++m)
    #pragma unroll
    for (int n = 0; n < 4; ++n)
      #pragma unroll
      for (int r = 0; r < 4; ++r) {
        int row = rowA0 + wrow + m*16 + g*4 + r;   // C/D: row=(lane>>4)*4+reg
        int col = rowB0 + wcol + n*16 + c16;       //      col=lane&15
        C[(size_t)row * N + col] = (OutT)acc[m][n][r];
      }
}

// ---------------------------------------------------------------- RoPE + rank contraction
// P is bf16 (proj GEMM writes bf16 directly).
__global__ void qkv_kernel(const bf16* __restrict__ P, const float* __restrict__ fcos,
                           const float* __restrict__ fsin, bf16* __restrict__ qat,
                           bf16* __restrict__ kat, bf16* __restrict__ vT) {
  const int m = blockIdx.x;
  const int b = m >> 11, s = m & 2047;
  const int d = threadIdx.x;
  __shared__ float Aq[48]; __shared__ float Ak[2]; __shared__ float Av[2];
  const bf16* Prow = P + (size_t)m * NPAD;
  if (d < 48) Aq[d] = (float)Prow[d];
  else if (d < 50) Ak[d - 48] = (float)Prow[d];
  else if (d < 52) Av[d - 50] = (float)Prow[d];
  __syncthreads();
  const int dh = d & 127;
  const float co = fcos[s * 128 + dh], si = fsin[s * 128 + dh];
  const bool lo = (d < 128);
  float rq[6];
  #pragma unroll
  for (int r = 0; r < 6; ++r) {
    const bf16* Bq = Prow + 52 + r * 256;
    float x  = (float)Bq[d];
    float xp = (float)Bq[lo ? d + 128 : d - 128];
    rq[r] = lo ? (x * co - xp * si) : (xp * si + x * co);
  }
  #pragma unroll
  for (int h = 0; h < 8; ++h) {
    float a = 0.f;
    #pragma unroll
    for (int r = 0; r < 6; ++r) a += Aq[h * 6 + r] * rq[r];
    qat[((size_t)(b * 8 + h) * S_LEN + s) * DH + d] = (bf16)(a * QSCALE);
  }
  float ka = 0.f;
  #pragma unroll
  for (int r = 0; r < 2; ++r) {
    const bf16* Bk = Prow + 1588 + r * 256;
    float x  = (float)Bk[d];
    float xp = (float)Bk[lo ? d + 128 : d - 128];
    float rk = lo ? (x * co - xp * si) : (xp * si + x * co);
    ka += Ak[r] * rk;
  }
  kat[((size_t)b * S_LEN + s) * DH + d] = (bf16)(ka * 0.5f);
  float va = 0.f;
  #pragma unroll
  for (int r = 0; r < 2; ++r) va += Av[r] * (float)Prow[2100 + r * 256 + d];
  vT[((size_t)b * DH + d) * S_LEN + s] = (bf16)(va * 0.5f);
}

// ---------------------------------------------------------------- flash attention (R6-exact)
// Fixed-max softmax (softcap bounds scores to +-50 => m=50 exactly):
// p = exp(-100*rcp(exp(0.04x)+1)).  8 waves/block: waves 0-3 take KV cols
// [0,32) of each 64-col step, waves 4-7 take [32,64); K/V staged once and
// shared.  Each block processes the uniform pair of q-tiles (31-p, p):
// 33 KV-steps for every block -> perfect load balance, no atomics.
// Halves merge once per tile via an LDS f32 reduction (reuses K buffer).
__launch_bounds__(512)
__global__ void attn_kernel(const bf16* __restrict__ qat, const bf16* __restrict__ kat,
                            const bf16* __restrict__ vT, bf16* __restrict__ O) {
  const int pr = (int)blockIdx.x;                  // pair index 0..15
  const int bh = (int)blockIdx.y;
  const int b = bh >> 3, h8 = bh & 7;
  const int t = threadIdx.x, lane = t & 63, w = t >> 6;
  const int g = lane >> 4, c16 = lane & 15;
  const int rw = w & 3, hf = w >> 2;               // row-group, KV-half
  __shared__ __align__(16) bf16 Kb[2][64 * 256];   // 64 KB (also reused as Fc)
  __shared__ __align__(16) bf16 Vb[2][256 * 64];   // 64 KB
  __shared__ __align__(16) bf16 Pl[8][16 * 40];    // 10 KB per-wave P
  __shared__ f32x4 Lc[4][64];                      // 4 KB l-partials
  float* Fc = (float*)&Kb[0][0];                   // 64 KB f32 combine area

  const int ks_r = lane >> 5, ks_x = lane & 31;    // K stage: 2 rows/instr
  const int vs_r = lane >> 3, vs_x = lane & 7;     // V stage: 8 rows/instr
  const size_t kbase = (size_t)b * S_LEN * DH;
  const size_t vbase = (size_t)b * DH * S_LEN;

  auto stage = [&](int buf, int j0) {
    #pragma unroll
    for (int i = 0; i < 4; ++i) {                  // K tile 64x256, swz unit^(row&7)
      int lr = w * 8 + i * 2 + ks_r;
      int gx = ks_x ^ (lr & 7);
      gload16(kat + kbase + (size_t)(j0 + lr) * DH + gx * 8,
              &Kb[buf][(w * 8 + i * 2) * 256]);
    }
    #pragma unroll
    for (int i = 0; i < 4; ++i) {                  // V^T tile 256x64, swz unit^(row&7)
      int lr = w * 32 + i * 8 + vs_r;
      int gx = vs_x ^ (lr & 7);
      gload16(vT + vbase + (size_t)lr * S_LEN + j0 + gx * 8,
              &Vb[buf][(w * 32 + i * 8) * 64]);
    }
  };

  f32x4 z = {0.f, 0.f, 0.f, 0.f};
  const int kswz = c16 & 7;

  #pragma unroll 1
  for (int half = 0; half < 2; ++half) {
    const int qt = half ? pr : 31 - pr;            // heavy tile first
    const int q0 = qt * 64;
    const int rowg0 = q0 + rw * 16 + g * 4;

    bf16x8 qf[8];
    {
      const bf16* qrow = qat + ((size_t)bh * S_LEN + q0 + rw * 16 + c16) * DH;
      #pragma unroll
      for (int kf = 0; kf < 8; ++kf)
        qf[kf] = *reinterpret_cast<const bf16x8*>(qrow + kf * 32 + g * 8);
    }
    f32x4 accO[16];
    #pragma unroll
    for (int i = 0; i < 16; ++i) accO[i] = z;
    float lr4[4] = {0.f, 0.f, 0.f, 0.f};

    const int nst = qt + 1;                        // KVBLK=64 steps
    stage(0, 0);
    __syncthreads();

    for (int ts = 0; ts < nst; ++ts) {
      const int cb = ts & 1, nb = cb ^ 1;
      const int j0 = ts * 64;
      if (ts + 1 < nst) stage(nb, j0 + 64);        // async prefetch next tile

      f32x4 sc[2];
      #pragma unroll
      for (int nt = 0; nt < 2; ++nt) {             // QK^T: 16 rows x 32 cols (this half)
        f32x4 a = z;
        const int rk = hf * 32 + nt * 16 + c16;
        __builtin_amdgcn_s_setprio(1);
        #pragma unroll
        for (int kf = 0; kf < 8; ++kf) {
          bf16x8 kb = *reinterpret_cast<const bf16x8*>(
              &Kb[cb][rk * 256 + ((kf * 4 + g) ^ kswz) * 8]);
          a = __builtin_amdgcn_mfma_f32_16x16x32_bf16(qf[kf], kb, a, 0, 0, 0);
        }
        __builtin_amdgcn_s_setprio(0);
        sc[nt] = a;
      }
      // softcap + causal + fixed-max exp -> P (bf16, wave-private LDS)
      #pragma unroll
      for (int nt = 0; nt < 2; ++nt) {
        int col = j0 + hf * 32 + nt * 16 + c16;
        #pragma unroll
        for (int r = 0; r < 4; ++r) {
          float x = sc[nt][r];
          float e2 = __expf(x * 0.04f);
          float p = (col <= rowg0 + r)
                      ? __expf(-100.f * __frcp_rn(e2 + 1.f))
                      : 0.f;
          lr4[r] += p;
          Pl[w][(g * 4 + r) * 40 + nt * 16 + c16] = (bf16)p;
        }
      }
      // PV: O[16x256] += P[16x32] @ V[32 cols of this half][256]
      bf16x8 pa = *reinterpret_cast<const bf16x8*>(&Pl[w][c16 * 40 + g * 8]);
      __builtin_amdgcn_s_setprio(1);
      #pragma unroll
      for (int dt = 0; dt < 16; ++dt) {
        int vrow = dt * 16 + c16;
        bf16x8 vb = *reinterpret_cast<const bf16x8*>(
            &Vb[cb][vrow * 64 + ((hf * 4 + g) ^ (vrow & 7)) * 8]);
        accO[dt] = __builtin_amdgcn_mfma_f32_16x16x32_bf16(pa, vb, accO[dt], 0, 0, 0);
      }
      __builtin_amdgcn_s_setprio(0);
      __syncthreads();                             // drains stage + read fences
    }

    // merge KV-halves: waves 4-7 dump partials, waves 0-3 add + write O
    if (hf == 1) {
      #pragma unroll
      for (int dt = 0; dt < 16; ++dt)
        #pragma unroll
        for (int r = 0; r < 4; ++r)
          Fc[rw * 4096 + (g * 4 + r) * 256 + dt * 16 + c16] = accO[dt][r];
      f32x4 lv = {lr4[0], lr4[1], lr4[2], lr4[3]};
      Lc[rw][lane] = lv;
    }
    __syncthreads();
    if (hf == 0) {
      f32x4 lo = Lc[rw][lane];
      #pragma unroll
      for (int r = 0; r < 4; ++r) lr4[r] += lo[r];
      #pragma unroll
      for (int dt = 0; dt < 16; ++dt)
        #pragma unroll
        for (int r = 0; r < 4; ++r)
          accO[dt][r] += Fc[rw * 4096 + (g * 4 + r) * 256 + dt * 16 + c16];
      #pragma unroll
      for (int r = 0; r < 4; ++r) {
        float l = lr4[r];
        l += __shfl_xor(l, 1);
        l += __shfl_xor(l, 2);
        l += __shfl_xor(l, 4);
        l += __shfl_xor(l, 8);
        float inv = 1.f / l;
        #pragma unroll
        for (int dt = 0; dt < 16; ++dt)
          O[((size_t)b * S_LEN + rowg0 + r) * (size_t)(NH * DH) + h8 * DH + dt * 16 + c16] =
              (bf16)(accO[dt][r] * inv);
      }
    }
    __syncthreads();                               // Fc free before next half's stage
  }
}

// ---------------------------------------------------------------- launch
extern "C" void kernel_launch(void* const* d_in, const int* in_sizes, int n_in,
                              void* d_out, int out_size, void* d_ws, size_t ws_size,
                              hipStream_t stream) {
  (void)in_sizes; (void)n_in; (void)out_size; (void)ws_size;
  const float* hs   = (const float*)d_in[0];
  const float* fcos = (const float*)d_in[1];
  const float* fsin = (const float*)d_in[2];
  // d_in[3] mask (analytic causal), d_in[4] kv_write_indices (arange) -- unused
  const float* Wq = (const float*)d_in[5];
  const float* Wk = (const float*)d_in[6];
  const float* Wv = (const float*)d_in[7];
  const float* Bq = (const float*)d_in[8];
  const float* Bk = (const float*)d_in[9];
  const float* Bv = (const float*)d_in[10];
  const float* Wo = (const float*)d_in[11];

  char* ws = (char*)d_ws;
  size_t off = 0;
  auto alloc = [&](size_t bytes) {
    void* p = ws + off;
    off += (bytes + 255) & ~(size_t)255;
    return p;
  };
  bf16*  Xbf  = (bf16*) alloc((size_t)MTOT * HIDN * 2);           // 16.8 MB
  bf16*  Wcat = (bf16*) alloc((size_t)NPAD * HIDN * 2);           // 11.0 MB
  bf16*  Wob  = (bf16*) alloc((size_t)HIDN * HIDN * 2);           //  8.4 MB
  bf16*  Pb   = (bf16*) alloc((size_t)MTOT * NPAD * 2);           // 22.0 MB
  bf16*  qat  = (bf16*) alloc((size_t)BATCH * NH * S_LEN * DH * 2); // 16.8 MB
  bf16*  kat  = (bf16*) alloc((size_t)BATCH * S_LEN * DH * 2);    //  2.1 MB
  bf16*  vT   = (bf16*) alloc((size_t)BATCH * DH * S_LEN * 2);    //  2.1 MB
  bf16*  Oat  = (bf16*) alloc((size_t)MTOT * NH * DH * 2);        // 16.8 MB
  float* out  = (float*)d_out;

  cast_x_kernel<<<dim3(MTOT * HIDN / 8 / 256), dim3(256), 0, stream>>>(hs, Xbf);
  cast_w_kernel<<<dim3(NPAD + HIDN), dim3(256), 0, stream>>>(Wq, Wk, Wv, Bq, Bk, Bv, Wo, Wcat, Wob);
  gemm_bt_kernel<bf16><<<dim3(NPAD / 128, MTOT / 256), dim3(512), 0, stream>>>(Xbf, Wcat, Pb, HIDN, NPAD);
  qkv_kernel<<<dim3(MTOT), dim3(256), 0, stream>>>(Pb, fcos, fsin, qat, kat, vT);
  attn_kernel<<<dim3(16, BATCH * NH), dim3(512), 0, stream>>>(qat, kat, vT, Oat);
  gemm_bt_kernel<float><<<dim3(HIDN / 128, MTOT / 256), dim3(512), 0, stream>>>(Oat, Wob, out, HIDN, HIDN);
}

// Round 13
// 221.917 us; speedup vs baseline: 1.1390x; 1.1390x over previous
//
#include <hip/hip_runtime.h>
#include <hip/hip_bf16.h>
#include <stdint.h>

typedef __bf16 bf16;
typedef __bf16 bf16x8 __attribute__((ext_vector_type(8)));
typedef float  f32x4  __attribute__((ext_vector_type(4)));

static constexpr int S_LEN = 2048;
static constexpr int HIDN  = 2048;
static constexpr int BATCH = 2;
static constexpr int MTOT  = BATCH * S_LEN;   // 4096
static constexpr int NH    = 8;
static constexpr int DH    = 256;
static constexpr int NPAD  = 2688;            // 2612 proj cols padded to 21*128
static constexpr float QSCALE = 0.0625f / 6.0f;  // SCALING(1/16) * 1/RQ

__device__ __forceinline__ void gload16(const bf16* g, const bf16* l) {
  __builtin_amdgcn_global_load_lds(
      (const __attribute__((address_space(1))) void*)g,
      (__attribute__((address_space(3))) void*)l, 16, 0, 0);
}

// ---------------------------------------------------------------- casts
__global__ void cast_x_kernel(const float* __restrict__ in, bf16* __restrict__ out) {
  int i = blockIdx.x * blockDim.x + threadIdx.x;          // one thread per 8 elems
  const float4* p = reinterpret_cast<const float4*>(in) + 2 * (size_t)i;
  float4 a = p[0], b = p[1];
  bf16x8 o;
  o[0]=(bf16)a.x; o[1]=(bf16)a.y; o[2]=(bf16)a.z; o[3]=(bf16)a.w;
  o[4]=(bf16)b.x; o[5]=(bf16)b.y; o[6]=(bf16)b.z; o[7]=(bf16)b.w;
  reinterpret_cast<bf16x8*>(out)[i] = o;
}

__global__ void cast_w_kernel(const float* __restrict__ Wq, const float* __restrict__ Wk,
                              const float* __restrict__ Wv, const float* __restrict__ Bq,
                              const float* __restrict__ Bk, const float* __restrict__ Bv,
                              const float* __restrict__ Wo, bf16* __restrict__ Wcat,
                              bf16* __restrict__ Wob) {
  int row = blockIdx.x;
  int c = threadIdx.x * 8;
  const float* src = nullptr;
  bf16* dst;
  if (row < NPAD) {
    dst = Wcat + (size_t)row * HIDN;
    if      (row <   48) src = Wq + (size_t)row        * HIDN;
    else if (row <   50) src = Wk + (size_t)(row-  48) * HIDN;
    else if (row <   52) src = Wv + (size_t)(row-  50) * HIDN;
    else if (row < 1588) src = Bq + (size_t)(row-  52) * HIDN;
    else if (row < 2100) src = Bk + (size_t)(row-1588) * HIDN;
    else if (row < 2612) src = Bv + (size_t)(row-2100) * HIDN;
  } else {
    dst = Wob + (size_t)(row - NPAD) * HIDN;
    src = Wo + (size_t)(row - NPAD) * HIDN;
  }
  bf16x8 o;
  if (src) {
    const float4* p = reinterpret_cast<const float4*>(src + c);
    float4 a = p[0], b = p[1];
    o[0]=(bf16)a.x; o[1]=(bf16)a.y; o[2]=(bf16)a.z; o[3]=(bf16)a.w;
    o[4]=(bf16)b.x; o[5]=(bf16)b.y; o[6]=(bf16)b.z; o[7]=(bf16)b.w;
  } else {
    #pragma unroll
    for (int j = 0; j < 8; ++j) o[j] = (bf16)0.f;
  }
  *reinterpret_cast<bf16x8*>(dst + c) = o;
}

// ---------------------------------------------------------------- GEMM (B^T input), 4-wave 128^2
// T3 2-phase + rule-#21 both-sides swizzle (R11-exact).
template <typename OutT>
__launch_bounds__(256)
__global__ void gemm_bt_kernel(const bf16* __restrict__ A, const bf16* __restrict__ Bt,
                               OutT* __restrict__ C, int K, int N) {
  __shared__ __align__(16) bf16 As[2][128 * 64];
  __shared__ __align__(16) bf16 Bs[2][128 * 64];
  const int t = threadIdx.x;
  const int lane = t & 63, wid = t >> 6;
  const int g = lane >> 4, c16 = lane & 15;
  const int nwg = (int)(gridDim.x * gridDim.y);
  int flat = (int)(blockIdx.y * gridDim.x + blockIdx.x);
  flat = (flat & 7) * (nwg >> 3) + (flat >> 3);            // XCD swizzle
  const int bxs = flat % (int)gridDim.x, bys = flat / (int)gridDim.x;
  const int rowA0 = bys * 128, rowB0 = bxs * 128;
  const int wrow = (wid >> 1) * 64, wcol = (wid & 1) * 64;
  const int srow = (lane >> 3), sunit = lane & 7;        // staging: 8 rows x 8 units
  const int sgx = (sunit ^ (srow & 7)) * 8;              // inverse-swizzled global col
  const int rswz = c16 & 7;                              // read-side swizzle key
  f32x4 z = {0.f, 0.f, 0.f, 0.f};
  f32x4 acc[4][4];
  #pragma unroll
  for (int m = 0; m < 4; ++m)
    #pragma unroll
    for (int n = 0; n < 4; ++n) acc[m][n] = z;

  auto stage = [&](int buf, int kt) {
    #pragma unroll
    for (int i = 0; i < 4; ++i) {                 // wave stages rows [wid*32, wid*32+32)
      int r0 = wid * 32 + i * 8;
      gload16(A + (size_t)(rowA0 + r0 + srow) * K + kt + sgx, &As[buf][r0 * 64]);
      gload16(Bt + (size_t)(rowB0 + r0 + srow) * K + kt + sgx, &Bs[buf][r0 * 64]);
    }
  };

  const int nk = K >> 6;
  stage(0, 0);
  __syncthreads();
  for (int ti = 0; ti < nk; ++ti) {
    const int cb = ti & 1;
    if (ti + 1 < nk) stage(cb ^ 1, (ti + 1) * 64);       // prefetch next K-tile
    #pragma unroll
    for (int ks = 0; ks < 2; ++ks) {
      bf16x8 af[4], bfr[4];
      #pragma unroll
      for (int m = 0; m < 4; ++m)
        af[m] = *reinterpret_cast<const bf16x8*>(
            &As[cb][(wrow + m*16 + c16) * 64 + ((ks*4 + g) ^ rswz) * 8]);
      #pragma unroll
      for (int n = 0; n < 4; ++n)
        bfr[n] = *reinterpret_cast<const bf16x8*>(
            &Bs[cb][(wcol + n*16 + c16) * 64 + ((ks*4 + g) ^ rswz) * 8]);
      __builtin_amdgcn_s_setprio(1);
      #pragma unroll
      for (int m = 0; m < 4; ++m)
        #pragma unroll
        for (int n = 0; n < 4; ++n)
          acc[m][n] = __builtin_amdgcn_mfma_f32_16x16x32_bf16(af[m], bfr[n], acc[m][n], 0, 0, 0);
      __builtin_amdgcn_s_setprio(0);
    }
    __syncthreads();                                     // drains prefetch (landed under MFMA)
  }
  #pragma unroll
  for (int m = 0; m < 4; ++m)
    #pragma unroll
    for (int n = 0; n < 4; ++n)
      #pragma unroll
      for (int r = 0; r < 4; ++r) {
        int row = rowA0 + wrow + m*16 + g*4 + r;   // C/D: row=(lane>>4)*4+reg
        int col = rowB0 + wcol + n*16 + c16;       //      col=lane&15
        C[(size_t)row * N + col] = (OutT)acc[m][n][r];
      }
}

// ---------------------------------------------------------------- GEMM (B^T input), 8-wave 128^2
// Same tile, LDS (64KB -> 2 blocks/CU) and sync structure as the 4-wave
// version, but 8 waves of 32x64 each -> 16 waves/CU (pure TLP A/B test).
template <typename OutT>
__launch_bounds__(512)
__global__ void gemm_bt8_kernel(const bf16* __restrict__ A, const bf16* __restrict__ Bt,
                                OutT* __restrict__ C, int K, int N) {
  __shared__ __align__(16) bf16 As[2][128 * 64];
  __shared__ __align__(16) bf16 Bs[2][128 * 64];
  const int t = threadIdx.x;
  const int lane = t & 63, wid = t >> 6;
  const int g = lane >> 4, c16 = lane & 15;
  const int nwg = (int)(gridDim.x * gridDim.y);
  int flat = (int)(blockIdx.y * gridDim.x + blockIdx.x);
  flat = (flat & 7) * (nwg >> 3) + (flat >> 3);            // XCD swizzle
  const int bxs = flat % (int)gridDim.x, bys = flat / (int)gridDim.x;
  const int rowA0 = bys * 128, rowB0 = bxs * 128;
  const int wrow = (wid >> 1) * 32, wcol = (wid & 1) * 64; // 4M x 2N, 32x64 per wave
  const int srow = (lane >> 3), sunit = lane & 7;          // staging: 8 rows x 8 units
  const int sgx = (sunit ^ (srow & 7)) * 8;                // inverse-swizzled global col
  const int rswz = c16 & 7;                                // read-side swizzle key
  f32x4 z = {0.f, 0.f, 0.f, 0.f};
  f32x4 acc[2][4];
  #pragma unroll
  for (int m = 0; m < 2; ++m)
    #pragma unroll
    for (int n = 0; n < 4; ++n) acc[m][n] = z;

  auto stage = [&](int buf, int kt) {
    #pragma unroll
    for (int i = 0; i < 2; ++i) {                 // wave stages rows [wid*16, wid*16+16)
      int r0 = wid * 16 + i * 8;
      gload16(A + (size_t)(rowA0 + r0 + srow) * K + kt + sgx, &As[buf][r0 * 64]);
      gload16(Bt + (size_t)(rowB0 + r0 + srow) * K + kt + sgx, &Bs[buf][r0 * 64]);
    }
  };

  const int nk = K >> 6;
  stage(0, 0);
  __syncthreads();
  for (int ti = 0; ti < nk; ++ti) {
    const int cb = ti & 1;
    if (ti + 1 < nk) stage(cb ^ 1, (ti + 1) * 64);       // prefetch next K-tile
    #pragma unroll
    for (int ks = 0; ks < 2; ++ks) {
      bf16x8 af[2], bfr[4];
      #pragma unroll
      for (int m = 0; m < 2; ++m)
        af[m] = *reinterpret_cast<const bf16x8*>(
            &As[cb][(wrow + m*16 + c16) * 64 + ((ks*4 + g) ^ rswz) * 8]);
      #pragma unroll
      for (int n = 0; n < 4; ++n)
        bfr[n] = *reinterpret_cast<const bf16x8*>(
            &Bs[cb][(wcol + n*16 + c16) * 64 + ((ks*4 + g) ^ rswz) * 8]);
      __builtin_amdgcn_s_setprio(1);
      #pragma unroll
      for (int m = 0; m < 2; ++m)
        #pragma unroll
        for (int n = 0; n < 4; ++n)
          acc[m][n] = __builtin_amdgcn_mfma_f32_16x16x32_bf16(af[m], bfr[n], acc[m][n], 0, 0, 0);
      __builtin_amdgcn_s_setprio(0);
    }
    __syncthreads();                                     // drains prefetch (landed under MFMA)
  }
  #pragma unroll
  for (int m = 0; m < 2; ++m)
    #pragma unroll
    for (int n = 0; n < 4; ++n)
      #pragma unroll
      for (int r = 0; r < 4; ++r) {
        int row = rowA0 + wrow + m*16 + g*4 + r;   // C/D: row=(lane>>4)*4+reg
        int col = rowB0 + wcol + n*16 + c16;       //      col=lane&15
        C[(size_t)row * N + col] = (OutT)acc[m][n][r];
      }
}

// ---------------------------------------------------------------- RoPE + rank contraction
// P is bf16 (proj GEMM writes bf16 directly).
__global__ void qkv_kernel(const bf16* __restrict__ P, const float* __restrict__ fcos,
                           const float* __restrict__ fsin, bf16* __restrict__ qat,
                           bf16* __restrict__ kat, bf16* __restrict__ vT) {
  const int m = blockIdx.x;
  const int b = m >> 11, s = m & 2047;
  const int d = threadIdx.x;
  __shared__ float Aq[48]; __shared__ float Ak[2]; __shared__ float Av[2];
  const bf16* Prow = P + (size_t)m * NPAD;
  if (d < 48) Aq[d] = (float)Prow[d];
  else if (d < 50) Ak[d - 48] = (float)Prow[d];
  else if (d < 52) Av[d - 50] = (float)Prow[d];
  __syncthreads();
  const int dh = d & 127;
  const float co = fcos[s * 128 + dh], si = fsin[s * 128 + dh];
  const bool lo = (d < 128);
  float rq[6];
  #pragma unroll
  for (int r = 0; r < 6; ++r) {
    const bf16* Bq = Prow + 52 + r * 256;
    float x  = (float)Bq[d];
    float xp = (float)Bq[lo ? d + 128 : d - 128];
    rq[r] = lo ? (x * co - xp * si) : (xp * si + x * co);
  }
  #pragma unroll
  for (int h = 0; h < 8; ++h) {
    float a = 0.f;
    #pragma unroll
    for (int r = 0; r < 6; ++r) a += Aq[h * 6 + r] * rq[r];
    qat[((size_t)(b * 8 + h) * S_LEN + s) * DH + d] = (bf16)(a * QSCALE);
  }
  float ka = 0.f;
  #pragma unroll
  for (int r = 0; r < 2; ++r) {
    const bf16* Bk = Prow + 1588 + r * 256;
    float x  = (float)Bk[d];
    float xp = (float)Bk[lo ? d + 128 : d - 128];
    float rk = lo ? (x * co - xp * si) : (xp * si + x * co);
    ka += Ak[r] * rk;
  }
  kat[((size_t)b * S_LEN + s) * DH + d] = (bf16)(ka * 0.5f);
  float va = 0.f;
  #pragma unroll
  for (int r = 0; r < 2; ++r) va += Av[r] * (float)Prow[2100 + r * 256 + d];
  vT[((size_t)b * DH + d) * S_LEN + s] = (bf16)(va * 0.5f);
}

// ---------------------------------------------------------------- flash attention (R6-exact)
// Fixed-max softmax (softcap bounds scores to +-50 => m=50 exactly):
// p = exp(-100*rcp(exp(0.04x)+1)).  8 waves/block: waves 0-3 take KV cols
// [0,32) of each 64-col step, waves 4-7 take [32,64); K/V staged once and
// shared.  Each block processes the uniform pair of q-tiles (31-p, p):
// 33 KV-steps for every block -> perfect load balance, no atomics.
// Halves merge once per tile via an LDS f32 reduction (reuses K buffer).
__launch_bounds__(512)
__global__ void attn_kernel(const bf16* __restrict__ qat, const bf16* __restrict__ kat,
                            const bf16* __restrict__ vT, bf16* __restrict__ O) {
  const int pr = (int)blockIdx.x;                  // pair index 0..15
  const int bh = (int)blockIdx.y;
  const int b = bh >> 3, h8 = bh & 7;
  const int t = threadIdx.x, lane = t & 63, w = t >> 6;
  const int g = lane >> 4, c16 = lane & 15;
  const int rw = w & 3, hf = w >> 2;               // row-group, KV-half
  __shared__ __align__(16) bf16 Kb[2][64 * 256];   // 64 KB (also reused as Fc)
  __shared__ __align__(16) bf16 Vb[2][256 * 64];   // 64 KB
  __shared__ __align__(16) bf16 Pl[8][16 * 40];    // 10 KB per-wave P
  __shared__ f32x4 Lc[4][64];                      // 4 KB l-partials
  float* Fc = (float*)&Kb[0][0];                   // 64 KB f32 combine area

  const int ks_r = lane >> 5, ks_x = lane & 31;    // K stage: 2 rows/instr
  const int vs_r = lane >> 3, vs_x = lane & 7;     // V stage: 8 rows/instr
  const size_t kbase = (size_t)b * S_LEN * DH;
  const size_t vbase = (size_t)b * DH * S_LEN;

  auto stage = [&](int buf, int j0) {
    #pragma unroll
    for (int i = 0; i < 4; ++i) {                  // K tile 64x256, swz unit^(row&7)
      int lr = w * 8 + i * 2 + ks_r;
      int gx = ks_x ^ (lr & 7);
      gload16(kat + kbase + (size_t)(j0 + lr) * DH + gx * 8,
              &Kb[buf][(w * 8 + i * 2) * 256]);
    }
    #pragma unroll
    for (int i = 0; i < 4; ++i) {                  // V^T tile 256x64, swz unit^(row&7)
      int lr = w * 32 + i * 8 + vs_r;
      int gx = vs_x ^ (lr & 7);
      gload16(vT + vbase + (size_t)lr * S_LEN + j0 + gx * 8,
              &Vb[buf][(w * 32 + i * 8) * 64]);
    }
  };

  f32x4 z = {0.f, 0.f, 0.f, 0.f};
  const int kswz = c16 & 7;

  #pragma unroll 1
  for (int half = 0; half < 2; ++half) {
    const int qt = half ? pr : 31 - pr;            // heavy tile first
    const int q0 = qt * 64;
    const int rowg0 = q0 + rw * 16 + g * 4;

    bf16x8 qf[8];
    {
      const bf16* qrow = qat + ((size_t)bh * S_LEN + q0 + rw * 16 + c16) * DH;
      #pragma unroll
      for (int kf = 0; kf < 8; ++kf)
        qf[kf] = *reinterpret_cast<const bf16x8*>(qrow + kf * 32 + g * 8);
    }
    f32x4 accO[16];
    #pragma unroll
    for (int i = 0; i < 16; ++i) accO[i] = z;
    float lr4[4] = {0.f, 0.f, 0.f, 0.f};

    const int nst = qt + 1;                        // KVBLK=64 steps
    stage(0, 0);
    __syncthreads();

    for (int ts = 0; ts < nst; ++ts) {
      const int cb = ts & 1, nb = cb ^ 1;
      const int j0 = ts * 64;
      if (ts + 1 < nst) stage(nb, j0 + 64);        // async prefetch next tile

      f32x4 sc[2];
      #pragma unroll
      for (int nt = 0; nt < 2; ++nt) {             // QK^T: 16 rows x 32 cols (this half)
        f32x4 a = z;
        const int rk = hf * 32 + nt * 16 + c16;
        __builtin_amdgcn_s_setprio(1);
        #pragma unroll
        for (int kf = 0; kf < 8; ++kf) {
          bf16x8 kb = *reinterpret_cast<const bf16x8*>(
              &Kb[cb][rk * 256 + ((kf * 4 + g) ^ kswz) * 8]);
          a = __builtin_amdgcn_mfma_f32_16x16x32_bf16(qf[kf], kb, a, 0, 0, 0);
        }
        __builtin_amdgcn_s_setprio(0);
        sc[nt] = a;
      }
      // softcap + causal + fixed-max exp -> P (bf16, wave-private LDS)
      #pragma unroll
      for (int nt = 0; nt < 2; ++nt) {
        int col = j0 + hf * 32 + nt * 16 + c16;
        #pragma unroll
        for (int r = 0; r < 4; ++r) {
          float x = sc[nt][r];
          float e2 = __expf(x * 0.04f);
          float p = (col <= rowg0 + r)
                      ? __expf(-100.f * __frcp_rn(e2 + 1.f))
                      : 0.f;
          lr4[r] += p;
          Pl[w][(g * 4 + r) * 40 + nt * 16 + c16] = (bf16)p;
        }
      }
      // PV: O[16x256] += P[16x32] @ V[32 cols of this half][256]
      bf16x8 pa = *reinterpret_cast<const bf16x8*>(&Pl[w][c16 * 40 + g * 8]);
      __builtin_amdgcn_s_setprio(1);
      #pragma unroll
      for (int dt = 0; dt < 16; ++dt) {
        int vrow = dt * 16 + c16;
        bf16x8 vb = *reinterpret_cast<const bf16x8*>(
            &Vb[cb][vrow * 64 + ((hf * 4 + g) ^ (vrow & 7)) * 8]);
        accO[dt] = __builtin_amdgcn_mfma_f32_16x16x32_bf16(pa, vb, accO[dt], 0, 0, 0);
      }
      __builtin_amdgcn_s_setprio(0);
      __syncthreads();                             // drains stage + read fences
    }

    // merge KV-halves: waves 4-7 dump partials, waves 0-3 add + write O
    if (hf == 1) {
      #pragma unroll
      for (int dt = 0; dt < 16; ++dt)
        #pragma unroll
        for (int r = 0; r < 4; ++r)
          Fc[rw * 4096 + (g * 4 + r) * 256 + dt * 16 + c16] = accO[dt][r];
      f32x4 lv = {lr4[0], lr4[1], lr4[2], lr4[3]};
      Lc[rw][lane] = lv;
    }
    __syncthreads();
    if (hf == 0) {
      f32x4 lo = Lc[rw][lane];
      #pragma unroll
      for (int r = 0; r < 4; ++r) lr4[r] += lo[r];
      #pragma unroll
      for (int dt = 0; dt < 16; ++dt)
        #pragma unroll
        for (int r = 0; r < 4; ++r)
          accO[dt][r] += Fc[rw * 4096 + (g * 4 + r) * 256 + dt * 16 + c16];
      #pragma unroll
      for (int r = 0; r < 4; ++r) {
        float l = lr4[r];
        l += __shfl_xor(l, 1);
        l += __shfl_xor(l, 2);
        l += __shfl_xor(l, 4);
        l += __shfl_xor(l, 8);
        float inv = 1.f / l;
        #pragma unroll
        for (int dt = 0; dt < 16; ++dt)
          O[((size_t)b * S_LEN + rowg0 + r) * (size_t)(NH * DH) + h8 * DH + dt * 16 + c16] =
              (bf16)(accO[dt][r] * inv);
      }
    }
    __syncthreads();                               // Fc free before next half's stage
  }
}

// ---------------------------------------------------------------- launch
extern "C" void kernel_launch(void* const* d_in, const int* in_sizes, int n_in,
                              void* d_out, int out_size, void* d_ws, size_t ws_size,
                              hipStream_t stream) {
  (void)in_sizes; (void)n_in; (void)out_size; (void)ws_size;
  const float* hs   = (const float*)d_in[0];
  const float* fcos = (const float*)d_in[1];
  const float* fsin = (const float*)d_in[2];
  // d_in[3] mask (analytic causal), d_in[4] kv_write_indices (arange) -- unused
  const float* Wq = (const float*)d_in[5];
  const float* Wk = (const float*)d_in[6];
  const float* Wv = (const float*)d_in[7];
  const float* Bq = (const float*)d_in[8];
  const float* Bk = (const float*)d_in[9];
  const float* Bv = (const float*)d_in[10];
  const float* Wo = (const float*)d_in[11];

  char* ws = (char*)d_ws;
  size_t off = 0;
  auto alloc = [&](size_t bytes) {
    void* p = ws + off;
    off += (bytes + 255) & ~(size_t)255;
    return p;
  };
  bf16*  Xbf  = (bf16*) alloc((size_t)MTOT * HIDN * 2);           // 16.8 MB
  bf16*  Wcat = (bf16*) alloc((size_t)NPAD * HIDN * 2);           // 11.0 MB
  bf16*  Wob  = (bf16*) alloc((size_t)HIDN * HIDN * 2);           //  8.4 MB
  bf16*  Pb   = (bf16*) alloc((size_t)MTOT * NPAD * 2);           // 22.0 MB
  bf16*  qat  = (bf16*) alloc((size_t)BATCH * NH * S_LEN * DH * 2); // 16.8 MB
  bf16*  kat  = (bf16*) alloc((size_t)BATCH * S_LEN * DH * 2);    //  2.1 MB
  bf16*  vT   = (bf16*) alloc((size_t)BATCH * DH * S_LEN * 2);    //  2.1 MB
  bf16*  Oat  = (bf16*) alloc((size_t)MTOT * NH * DH * 2);        // 16.8 MB
  float* out  = (float*)d_out;

  cast_x_kernel<<<dim3(MTOT * HIDN / 8 / 256), dim3(256), 0, stream>>>(hs, Xbf);
  cast_w_kernel<<<dim3(NPAD + HIDN), dim3(256), 0, stream>>>(Wq, Wk, Wv, Bq, Bk, Bv, Wo, Wcat, Wob);
  gemm_bt8_kernel<bf16><<<dim3(NPAD / 128, MTOT / 128), dim3(512), 0, stream>>>(Xbf, Wcat, Pb, HIDN, NPAD);
  qkv_kernel<<<dim3(MTOT), dim3(256), 0, stream>>>(Pb, fcos, fsin, qat, kat, vT);
  attn_kernel<<<dim3(16, BATCH * NH), dim3(512), 0, stream>>>(qat, kat, vT, Oat);
  gemm_bt_kernel<float><<<dim3(HIDN / 128, MTOT / 128), dim3(256), 0, stream>>>(Oat, Wob, out, HIDN, HIDN);
}

// Round 14
// 220.325 us; speedup vs baseline: 1.1473x; 1.0072x over previous
//
#include <hip/hip_runtime.h>
#include <hip/hip_bf16.h>
#include <stdint.h>

typedef __bf16 bf16;
typedef __bf16 bf16x8 __attribute__((ext_vector_type(8)));
typedef float  f32x4  __attribute__((ext_vector_type(4)));

static constexpr int S_LEN = 2048;
static constexpr int HIDN  = 2048;
static constexpr int BATCH = 2;
static constexpr int MTOT  = BATCH * S_LEN;   // 4096
static constexpr int NH    = 8;
static constexpr int DH    = 256;
static constexpr int NPAD  = 2688;            // 2612 proj cols padded to 21*128
static constexpr float QSCALE = 0.0625f / 6.0f;  // SCALING(1/16) * 1/RQ

__device__ __forceinline__ void gload16(const bf16* g, const bf16* l) {
  __builtin_amdgcn_global_load_lds(
      (const __attribute__((address_space(1))) void*)g,
      (__attribute__((address_space(3))) void*)l, 16, 0, 0);
}

// ---------------------------------------------------------------- casts
__global__ void cast_x_kernel(const float* __restrict__ in, bf16* __restrict__ out) {
  int i = blockIdx.x * blockDim.x + threadIdx.x;          // one thread per 8 elems
  const float4* p = reinterpret_cast<const float4*>(in) + 2 * (size_t)i;
  float4 a = p[0], b = p[1];
  bf16x8 o;
  o[0]=(bf16)a.x; o[1]=(bf16)a.y; o[2]=(bf16)a.z; o[3]=(bf16)a.w;
  o[4]=(bf16)b.x; o[5]=(bf16)b.y; o[6]=(bf16)b.z; o[7]=(bf16)b.w;
  reinterpret_cast<bf16x8*>(out)[i] = o;
}

__global__ void cast_w_kernel(const float* __restrict__ Wq, const float* __restrict__ Wk,
                              const float* __restrict__ Wv, const float* __restrict__ Bq,
                              const float* __restrict__ Bk, const float* __restrict__ Bv,
                              const float* __restrict__ Wo, bf16* __restrict__ Wcat,
                              bf16* __restrict__ Wob) {
  int row = blockIdx.x;
  int c = threadIdx.x * 8;
  const float* src = nullptr;
  bf16* dst;
  if (row < NPAD) {
    dst = Wcat + (size_t)row * HIDN;
    if      (row <   48) src = Wq + (size_t)row        * HIDN;
    else if (row <   50) src = Wk + (size_t)(row-  48) * HIDN;
    else if (row <   52) src = Wv + (size_t)(row-  50) * HIDN;
    else if (row < 1588) src = Bq + (size_t)(row-  52) * HIDN;
    else if (row < 2100) src = Bk + (size_t)(row-1588) * HIDN;
    else if (row < 2612) src = Bv + (size_t)(row-2100) * HIDN;
  } else {
    dst = Wob + (size_t)(row - NPAD) * HIDN;
    src = Wo + (size_t)(row - NPAD) * HIDN;
  }
  bf16x8 o;
  if (src) {
    const float4* p = reinterpret_cast<const float4*>(src + c);
    float4 a = p[0], b = p[1];
    o[0]=(bf16)a.x; o[1]=(bf16)a.y; o[2]=(bf16)a.z; o[3]=(bf16)a.w;
    o[4]=(bf16)b.x; o[5]=(bf16)b.y; o[6]=(bf16)b.z; o[7]=(bf16)b.w;
  } else {
    #pragma unroll
    for (int j = 0; j < 8; ++j) o[j] = (bf16)0.f;
  }
  *reinterpret_cast<bf16x8*>(dst + c) = o;
}

// ---------------------------------------------------------------- GEMM (B^T input), 8-wave 128^2
// 128^2 tile, 64KB LDS -> 2 blocks/CU, 8 waves of 32x64 (16 waves/CU).
// T3 2-phase dbuf + rule-#21 both-sides swizzle + XCD swizzle.
template <typename OutT>
__launch_bounds__(512)
__global__ void gemm_bt8_kernel(const bf16* __restrict__ A, const bf16* __restrict__ Bt,
                                OutT* __restrict__ C, int K, int N) {
  __shared__ __align__(16) bf16 As[2][128 * 64];
  __shared__ __align__(16) bf16 Bs[2][128 * 64];
  const int t = threadIdx.x;
  const int lane = t & 63, wid = t >> 6;
  const int g = lane >> 4, c16 = lane & 15;
  const int nwg = (int)(gridDim.x * gridDim.y);
  int flat = (int)(blockIdx.y * gridDim.x + blockIdx.x);
  flat = (flat & 7) * (nwg >> 3) + (flat >> 3);            // XCD swizzle
  const int bxs = flat % (int)gridDim.x, bys = flat / (int)gridDim.x;
  const int rowA0 = bys * 128, rowB0 = bxs * 128;
  const int wrow = (wid >> 1) * 32, wcol = (wid & 1) * 64; // 4M x 2N, 32x64 per wave
  const int srow = (lane >> 3), sunit = lane & 7;          // staging: 8 rows x 8 units
  const int sgx = (sunit ^ (srow & 7)) * 8;                // inverse-swizzled global col
  const int rswz = c16 & 7;                                // read-side swizzle key
  f32x4 z = {0.f, 0.f, 0.f, 0.f};
  f32x4 acc[2][4];
  #pragma unroll
  for (int m = 0; m < 2; ++m)
    #pragma unroll
    for (int n = 0; n < 4; ++n) acc[m][n] = z;

  auto stage = [&](int buf, int kt) {
    #pragma unroll
    for (int i = 0; i < 2; ++i) {                 // wave stages rows [wid*16, wid*16+16)
      int r0 = wid * 16 + i * 8;
      gload16(A + (size_t)(rowA0 + r0 + srow) * K + kt + sgx, &As[buf][r0 * 64]);
      gload16(Bt + (size_t)(rowB0 + r0 + srow) * K + kt + sgx, &Bs[buf][r0 * 64]);
    }
  };

  const int nk = K >> 6;
  stage(0, 0);
  __syncthreads();
  for (int ti = 0; ti < nk; ++ti) {
    const int cb = ti & 1;
    if (ti + 1 < nk) stage(cb ^ 1, (ti + 1) * 64);       // prefetch next K-tile
    #pragma unroll
    for (int ks = 0; ks < 2; ++ks) {
      bf16x8 af[2], bfr[4];
      #pragma unroll
      for (int m = 0; m < 2; ++m)
        af[m] = *reinterpret_cast<const bf16x8*>(
            &As[cb][(wrow + m*16 + c16) * 64 + ((ks*4 + g) ^ rswz) * 8]);
      #pragma unroll
      for (int n = 0; n < 4; ++n)
        bfr[n] = *reinterpret_cast<const bf16x8*>(
            &Bs[cb][(wcol + n*16 + c16) * 64 + ((ks*4 + g) ^ rswz) * 8]);
      __builtin_amdgcn_s_setprio(1);
      #pragma unroll
      for (int m = 0; m < 2; ++m)
        #pragma unroll
        for (int n = 0; n < 4; ++n)
          acc[m][n] = __builtin_amdgcn_mfma_f32_16x16x32_bf16(af[m], bfr[n], acc[m][n], 0, 0, 0);
      __builtin_amdgcn_s_setprio(0);
    }
    __syncthreads();                                     // drains prefetch (landed under MFMA)
  }
  #pragma unroll
  for (int m = 0; m < 2; ++m)
    #pragma unroll
    for (int n = 0; n < 4; ++n)
      #pragma unroll
      for (int r = 0; r < 4; ++r) {
        int row = rowA0 + wrow + m*16 + g*4 + r;   // C/D: row=(lane>>4)*4+reg
        int col = rowB0 + wcol + n*16 + c16;       //      col=lane&15
        C[(size_t)row * N + col] = (OutT)acc[m][n][r];
      }
}

// ---------------------------------------------------------------- RoPE + rank contraction
// P is bf16 (proj GEMM writes bf16 directly).
__global__ void qkv_kernel(const bf16* __restrict__ P, const float* __restrict__ fcos,
                           const float* __restrict__ fsin, bf16* __restrict__ qat,
                           bf16* __restrict__ kat, bf16* __restrict__ vT) {
  const int m = blockIdx.x;
  const int b = m >> 11, s = m & 2047;
  const int d = threadIdx.x;
  __shared__ float Aq[48]; __shared__ float Ak[2]; __shared__ float Av[2];
  const bf16* Prow = P + (size_t)m * NPAD;
  if (d < 48) Aq[d] = (float)Prow[d];
  else if (d < 50) Ak[d - 48] = (float)Prow[d];
  else if (d < 52) Av[d - 50] = (float)Prow[d];
  __syncthreads();
  const int dh = d & 127;
  const float co = fcos[s * 128 + dh], si = fsin[s * 128 + dh];
  const bool lo = (d < 128);
  float rq[6];
  #pragma unroll
  for (int r = 0; r < 6; ++r) {
    const bf16* Bq = Prow + 52 + r * 256;
    float x  = (float)Bq[d];
    float xp = (float)Bq[lo ? d + 128 : d - 128];
    rq[r] = lo ? (x * co - xp * si) : (xp * si + x * co);
  }
  #pragma unroll
  for (int h = 0; h < 8; ++h) {
    float a = 0.f;
    #pragma unroll
    for (int r = 0; r < 6; ++r) a += Aq[h * 6 + r] * rq[r];
    qat[((size_t)(b * 8 + h) * S_LEN + s) * DH + d] = (bf16)(a * QSCALE);
  }
  float ka = 0.f;
  #pragma unroll
  for (int r = 0; r < 2; ++r) {
    const bf16* Bk = Prow + 1588 + r * 256;
    float x  = (float)Bk[d];
    float xp = (float)Bk[lo ? d + 128 : d - 128];
    float rk = lo ? (x * co - xp * si) : (xp * si + x * co);
    ka += Ak[r] * rk;
  }
  kat[((size_t)b * S_LEN + s) * DH + d] = (bf16)(ka * 0.5f);
  float va = 0.f;
  #pragma unroll
  for (int r = 0; r < 2; ++r) va += Av[r] * (float)Prow[2100 + r * 256 + d];
  vT[((size_t)b * DH + d) * S_LEN + s] = (bf16)(va * 0.5f);
}

// ---------------------------------------------------------------- flash attention (R6-exact)
// Fixed-max softmax (softcap bounds scores to +-50 => m=50 exactly):
// p = exp(-100*rcp(exp(0.04x)+1)).  8 waves/block: waves 0-3 take KV cols
// [0,32) of each 64-col step, waves 4-7 take [32,64); K/V staged once and
// shared.  Each block processes the uniform pair of q-tiles (31-p, p):
// 33 KV-steps for every block -> perfect load balance, no atomics.
// Halves merge once per tile via an LDS f32 reduction (reuses K buffer).
__launch_bounds__(512)
__global__ void attn_kernel(const bf16* __restrict__ qat, const bf16* __restrict__ kat,
                            const bf16* __restrict__ vT, bf16* __restrict__ O) {
  const int pr = (int)blockIdx.x;                  // pair index 0..15
  const int bh = (int)blockIdx.y;
  const int b = bh >> 3, h8 = bh & 7;
  const int t = threadIdx.x, lane = t & 63, w = t >> 6;
  const int g = lane >> 4, c16 = lane & 15;
  const int rw = w & 3, hf = w >> 2;               // row-group, KV-half
  __shared__ __align__(16) bf16 Kb[2][64 * 256];   // 64 KB (also reused as Fc)
  __shared__ __align__(16) bf16 Vb[2][256 * 64];   // 64 KB
  __shared__ __align__(16) bf16 Pl[8][16 * 40];    // 10 KB per-wave P
  __shared__ f32x4 Lc[4][64];                      // 4 KB l-partials
  float* Fc = (float*)&Kb[0][0];                   // 64 KB f32 combine area

  const int ks_r = lane >> 5, ks_x = lane & 31;    // K stage: 2 rows/instr
  const int vs_r = lane >> 3, vs_x = lane & 7;     // V stage: 8 rows/instr
  const size_t kbase = (size_t)b * S_LEN * DH;
  const size_t vbase = (size_t)b * DH * S_LEN;

  auto stage = [&](int buf, int j0) {
    #pragma unroll
    for (int i = 0; i < 4; ++i) {                  // K tile 64x256, swz unit^(row&7)
      int lr = w * 8 + i * 2 + ks_r;
      int gx = ks_x ^ (lr & 7);
      gload16(kat + kbase + (size_t)(j0 + lr) * DH + gx * 8,
              &Kb[buf][(w * 8 + i * 2) * 256]);
    }
    #pragma unroll
    for (int i = 0; i < 4; ++i) {                  // V^T tile 256x64, swz unit^(row&7)
      int lr = w * 32 + i * 8 + vs_r;
      int gx = vs_x ^ (lr & 7);
      gload16(vT + vbase + (size_t)lr * S_LEN + j0 + gx * 8,
              &Vb[buf][(w * 32 + i * 8) * 64]);
    }
  };

  f32x4 z = {0.f, 0.f, 0.f, 0.f};
  const int kswz = c16 & 7;

  #pragma unroll 1
  for (int half = 0; half < 2; ++half) {
    const int qt = half ? pr : 31 - pr;            // heavy tile first
    const int q0 = qt * 64;
    const int rowg0 = q0 + rw * 16 + g * 4;

    bf16x8 qf[8];
    {
      const bf16* qrow = qat + ((size_t)bh * S_LEN + q0 + rw * 16 + c16) * DH;
      #pragma unroll
      for (int kf = 0; kf < 8; ++kf)
        qf[kf] = *reinterpret_cast<const bf16x8*>(qrow + kf * 32 + g * 8);
    }
    f32x4 accO[16];
    #pragma unroll
    for (int i = 0; i < 16; ++i) accO[i] = z;
    float lr4[4] = {0.f, 0.f, 0.f, 0.f};

    const int nst = qt + 1;                        // KVBLK=64 steps
    stage(0, 0);
    __syncthreads();

    for (int ts = 0; ts < nst; ++ts) {
      const int cb = ts & 1, nb = cb ^ 1;
      const int j0 = ts * 64;
      if (ts + 1 < nst) stage(nb, j0 + 64);        // async prefetch next tile

      f32x4 sc[2];
      #pragma unroll
      for (int nt = 0; nt < 2; ++nt) {             // QK^T: 16 rows x 32 cols (this half)
        f32x4 a = z;
        const int rk = hf * 32 + nt * 16 + c16;
        __builtin_amdgcn_s_setprio(1);
        #pragma unroll
        for (int kf = 0; kf < 8; ++kf) {
          bf16x8 kb = *reinterpret_cast<const bf16x8*>(
              &Kb[cb][rk * 256 + ((kf * 4 + g) ^ kswz) * 8]);
          a = __builtin_amdgcn_mfma_f32_16x16x32_bf16(qf[kf], kb, a, 0, 0, 0);
        }
        __builtin_amdgcn_s_setprio(0);
        sc[nt] = a;
      }
      // softcap + causal + fixed-max exp -> P (bf16, wave-private LDS)
      #pragma unroll
      for (int nt = 0; nt < 2; ++nt) {
        int col = j0 + hf * 32 + nt * 16 + c16;
        #pragma unroll
        for (int r = 0; r < 4; ++r) {
          float x = sc[nt][r];
          float e2 = __expf(x * 0.04f);
          float p = (col <= rowg0 + r)
                      ? __expf(-100.f * __frcp_rn(e2 + 1.f))
                      : 0.f;
          lr4[r] += p;
          Pl[w][(g * 4 + r) * 40 + nt * 16 + c16] = (bf16)p;
        }
      }
      // PV: O[16x256] += P[16x32] @ V[32 cols of this half][256]
      bf16x8 pa = *reinterpret_cast<const bf16x8*>(&Pl[w][c16 * 40 + g * 8]);
      __builtin_amdgcn_s_setprio(1);
      #pragma unroll
      for (int dt = 0; dt < 16; ++dt) {
        int vrow = dt * 16 + c16;
        bf16x8 vb = *reinterpret_cast<const bf16x8*>(
            &Vb[cb][vrow * 64 + ((hf * 4 + g) ^ (vrow & 7)) * 8]);
        accO[dt] = __builtin_amdgcn_mfma_f32_16x16x32_bf16(pa, vb, accO[dt], 0, 0, 0);
      }
      __builtin_amdgcn_s_setprio(0);
      __syncthreads();                             // drains stage + read fences
    }

    // merge KV-halves: waves 4-7 dump partials, waves 0-3 add + write O
    if (hf == 1) {
      #pragma unroll
      for (int dt = 0; dt < 16; ++dt)
        #pragma unroll
        for (int r = 0; r < 4; ++r)
          Fc[rw * 4096 + (g * 4 + r) * 256 + dt * 16 + c16] = accO[dt][r];
      f32x4 lv = {lr4[0], lr4[1], lr4[2], lr4[3]};
      Lc[rw][lane] = lv;
    }
    __syncthreads();
    if (hf == 0) {
      f32x4 lo = Lc[rw][lane];
      #pragma unroll
      for (int r = 0; r < 4; ++r) lr4[r] += lo[r];
      #pragma unroll
      for (int dt = 0; dt < 16; ++dt)
        #pragma unroll
        for (int r = 0; r < 4; ++r)
          accO[dt][r] += Fc[rw * 4096 + (g * 4 + r) * 256 + dt * 16 + c16];
      #pragma unroll
      for (int r = 0; r < 4; ++r) {
        float l = lr4[r];
        l += __shfl_xor(l, 1);
        l += __shfl_xor(l, 2);
        l += __shfl_xor(l, 4);
        l += __shfl_xor(l, 8);
        float inv = 1.f / l;
        #pragma unroll
        for (int dt = 0; dt < 16; ++dt)
          O[((size_t)b * S_LEN + rowg0 + r) * (size_t)(NH * DH) + h8 * DH + dt * 16 + c16] =
              (bf16)(accO[dt][r] * inv);
      }
    }
    __syncthreads();                               // Fc free before next half's stage
  }
}

// ---------------------------------------------------------------- launch
extern "C" void kernel_launch(void* const* d_in, const int* in_sizes, int n_in,
                              void* d_out, int out_size, void* d_ws, size_t ws_size,
                              hipStream_t stream) {
  (void)in_sizes; (void)n_in; (void)out_size; (void)ws_size;
  const float* hs   = (const float*)d_in[0];
  const float* fcos = (const float*)d_in[1];
  const float* fsin = (const float*)d_in[2];
  // d_in[3] mask (analytic causal), d_in[4] kv_write_indices (arange) -- unused
  const float* Wq = (const float*)d_in[5];
  const float* Wk = (const float*)d_in[6];
  const float* Wv = (const float*)d_in[7];
  const float* Bq = (const float*)d_in[8];
  const float* Bk = (const float*)d_in[9];
  const float* Bv = (const float*)d_in[10];
  const float* Wo = (const float*)d_in[11];

  char* ws = (char*)d_ws;
  size_t off = 0;
  auto alloc = [&](size_t bytes) {
    void* p = ws + off;
    off += (bytes + 255) & ~(size_t)255;
    return p;
  };
  bf16*  Xbf  = (bf16*) alloc((size_t)MTOT * HIDN * 2);           // 16.8 MB
  bf16*  Wcat = (bf16*) alloc((size_t)NPAD * HIDN * 2);           // 11.0 MB
  bf16*  Wob  = (bf16*) alloc((size_t)HIDN * HIDN * 2);           //  8.4 MB
  bf16*  Pb   = (bf16*) alloc((size_t)MTOT * NPAD * 2);           // 22.0 MB
  bf16*  qat  = (bf16*) alloc((size_t)BATCH * NH * S_LEN * DH * 2); // 16.8 MB
  bf16*  kat  = (bf16*) alloc((size_t)BATCH * S_LEN * DH * 2);    //  2.1 MB
  bf16*  vT   = (bf16*) alloc((size_t)BATCH * DH * S_LEN * 2);    //  2.1 MB
  bf16*  Oat  = (bf16*) alloc((size_t)MTOT * NH * DH * 2);        // 16.8 MB
  float* out  = (float*)d_out;

  cast_x_kernel<<<dim3(MTOT * HIDN / 8 / 256), dim3(256), 0, stream>>>(hs, Xbf);
  cast_w_kernel<<<dim3(NPAD + HIDN), dim3(256), 0, stream>>>(Wq, Wk, Wv, Bq, Bk, Bv, Wo, Wcat, Wob);
  gemm_bt8_kernel<bf16><<<dim3(NPAD / 128, MTOT / 128), dim3(512), 0, stream>>>(Xbf, Wcat, Pb, HIDN, NPAD);
  qkv_kernel<<<dim3(MTOT), dim3(256), 0, stream>>>(Pb, fcos, fsin, qat, kat, vT);
  attn_kernel<<<dim3(16, BATCH * NH), dim3(512), 0, stream>>>(qat, kat, vT, Oat);
  gemm_bt8_kernel<float><<<dim3(HIDN / 128, MTOT / 128), dim3(512), 0, stream>>>(Oat, Wob, out, HIDN, HIDN);
}

// Round 15
// 215.159 us; speedup vs baseline: 1.1748x; 1.0240x over previous
//
#include <hip/hip_runtime.h>
#include <hip/hip_bf16.h>
#include <stdint.h>

typedef __bf16 bf16;
typedef __bf16 bf16x8 __attribute__((ext_vector_type(8)));
typedef float  f32x4  __attribute__((ext_vector_type(4)));

static constexpr int S_LEN = 2048;
static constexpr int HIDN  = 2048;
static constexpr int BATCH = 2;
static constexpr int MTOT  = BATCH * S_LEN;   // 4096
static constexpr int NH    = 8;
static constexpr int DH    = 256;
static constexpr int NPAD  = 2688;            // 2612 proj cols padded to 21*128
static constexpr float QSCALE = 0.0625f / 6.0f;  // SCALING(1/16) * 1/RQ

__device__ __forceinline__ void gload16(const bf16* g, const bf16* l) {
  __builtin_amdgcn_global_load_lds(
      (const __attribute__((address_space(1))) void*)g,
      (__attribute__((address_space(3))) void*)l, 16, 0, 0);
}

// ---------------------------------------------------------------- merged casts
// blocks [0, 4096): hidden_states f32 -> bf16 (8 elems/thread)
// blocks [4096, 8832): weight-concat rows -> Wcat / Wob
__global__ void cast_all_kernel(const float* __restrict__ hs,
                                const float* __restrict__ Wq, const float* __restrict__ Wk,
                                const float* __restrict__ Wv, const float* __restrict__ Bq,
                                const float* __restrict__ Bk, const float* __restrict__ Bv,
                                const float* __restrict__ Wo, bf16* __restrict__ Xbf,
                                bf16* __restrict__ Wcat, bf16* __restrict__ Wob) {
  const int bid = blockIdx.x;
  if (bid < 4096) {
    int i = bid * blockDim.x + threadIdx.x;
    const float4* p = reinterpret_cast<const float4*>(hs) + 2 * (size_t)i;
    float4 a = p[0], b = p[1];
    bf16x8 o;
    o[0]=(bf16)a.x; o[1]=(bf16)a.y; o[2]=(bf16)a.z; o[3]=(bf16)a.w;
    o[4]=(bf16)b.x; o[5]=(bf16)b.y; o[6]=(bf16)b.z; o[7]=(bf16)b.w;
    reinterpret_cast<bf16x8*>(Xbf)[i] = o;
    return;
  }
  int row = bid - 4096;
  int c = threadIdx.x * 8;
  const float* src = nullptr;
  bf16* dst;
  if (row < NPAD) {
    dst = Wcat + (size_t)row * HIDN;
    if      (row <   48) src = Wq + (size_t)row        * HIDN;
    else if (row <   50) src = Wk + (size_t)(row-  48) * HIDN;
    else if (row <   52) src = Wv + (size_t)(row-  50) * HIDN;
    else if (row < 1588) src = Bq + (size_t)(row-  52) * HIDN;
    else if (row < 2100) src = Bk + (size_t)(row-1588) * HIDN;
    else if (row < 2612) src = Bv + (size_t)(row-2100) * HIDN;
  } else {
    dst = Wob + (size_t)(row - NPAD) * HIDN;
    src = Wo + (size_t)(row - NPAD) * HIDN;
  }
  bf16x8 o;
  if (src) {
    const float4* p = reinterpret_cast<const float4*>(src + c);
    float4 a = p[0], b = p[1];
    o[0]=(bf16)a.x; o[1]=(bf16)a.y; o[2]=(bf16)a.z; o[3]=(bf16)a.w;
    o[4]=(bf16)b.x; o[5]=(bf16)b.y; o[6]=(bf16)b.z; o[7]=(bf16)b.w;
  } else {
    #pragma unroll
    for (int j = 0; j < 8; ++j) o[j] = (bf16)0.f;
  }
  *reinterpret_cast<bf16x8*>(dst + c) = o;
}

// ---------------------------------------------------------------- GEMM (B^T input), 8-wave 128^2
// 128^2 tile, 64KB LDS -> 2 blocks/CU, 8 waves of 32x64 (16 waves/CU).
// T3 2-phase dbuf + rule-#21 both-sides swizzle + XCD swizzle.
template <typename OutT>
__launch_bounds__(512)
__global__ void gemm_bt8_kernel(const bf16* __restrict__ A, const bf16* __restrict__ Bt,
                                OutT* __restrict__ C, int K, int N) {
  __shared__ __align__(16) bf16 As[2][128 * 64];
  __shared__ __align__(16) bf16 Bs[2][128 * 64];
  const int t = threadIdx.x;
  const int lane = t & 63, wid = t >> 6;
  const int g = lane >> 4, c16 = lane & 15;
  const int nwg = (int)(gridDim.x * gridDim.y);
  int flat = (int)(blockIdx.y * gridDim.x + blockIdx.x);
  flat = (flat & 7) * (nwg >> 3) + (flat >> 3);            // XCD swizzle
  const int bxs = flat % (int)gridDim.x, bys = flat / (int)gridDim.x;
  const int rowA0 = bys * 128, rowB0 = bxs * 128;
  const int wrow = (wid >> 1) * 32, wcol = (wid & 1) * 64; // 4M x 2N, 32x64 per wave
  const int srow = (lane >> 3), sunit = lane & 7;          // staging: 8 rows x 8 units
  const int sgx = (sunit ^ (srow & 7)) * 8;                // inverse-swizzled global col
  const int rswz = c16 & 7;                                // read-side swizzle key
  f32x4 z = {0.f, 0.f, 0.f, 0.f};
  f32x4 acc[2][4];
  #pragma unroll
  for (int m = 0; m < 2; ++m)
    #pragma unroll
    for (int n = 0; n < 4; ++n) acc[m][n] = z;

  auto stage = [&](int buf, int kt) {
    #pragma unroll
    for (int i = 0; i < 2; ++i) {                 // wave stages rows [wid*16, wid*16+16)
      int r0 = wid * 16 + i * 8;
      gload16(A + (size_t)(rowA0 + r0 + srow) * K + kt + sgx, &As[buf][r0 * 64]);
      gload16(Bt + (size_t)(rowB0 + r0 + srow) * K + kt + sgx, &Bs[buf][r0 * 64]);
    }
  };

  const int nk = K >> 6;
  stage(0, 0);
  __syncthreads();
  for (int ti = 0; ti < nk; ++ti) {
    const int cb = ti & 1;
    if (ti + 1 < nk) stage(cb ^ 1, (ti + 1) * 64);       // prefetch next K-tile
    #pragma unroll
    for (int ks = 0; ks < 2; ++ks) {
      bf16x8 af[2], bfr[4];
      #pragma unroll
      for (int m = 0; m < 2; ++m)
        af[m] = *reinterpret_cast<const bf16x8*>(
            &As[cb][(wrow + m*16 + c16) * 64 + ((ks*4 + g) ^ rswz) * 8]);
      #pragma unroll
      for (int n = 0; n < 4; ++n)
        bfr[n] = *reinterpret_cast<const bf16x8*>(
            &Bs[cb][(wcol + n*16 + c16) * 64 + ((ks*4 + g) ^ rswz) * 8]);
      __builtin_amdgcn_s_setprio(1);
      #pragma unroll
      for (int m = 0; m < 2; ++m)
        #pragma unroll
        for (int n = 0; n < 4; ++n)
          acc[m][n] = __builtin_amdgcn_mfma_f32_16x16x32_bf16(af[m], bfr[n], acc[m][n], 0, 0, 0);
      __builtin_amdgcn_s_setprio(0);
    }
    __syncthreads();                                     // drains prefetch (landed under MFMA)
  }
  #pragma unroll
  for (int m = 0; m < 2; ++m)
    #pragma unroll
    for (int n = 0; n < 4; ++n)
      #pragma unroll
      for (int r = 0; r < 4; ++r) {
        int row = rowA0 + wrow + m*16 + g*4 + r;   // C/D: row=(lane>>4)*4+reg
        int col = rowB0 + wcol + n*16 + c16;       //      col=lane&15
        C[(size_t)row * N + col] = (OutT)acc[m][n][r];
      }
}

// ---------------------------------------------------------------- RoPE + rank contraction
// P is bf16 (proj GEMM writes bf16 directly).
__global__ void qkv_kernel(const bf16* __restrict__ P, const float* __restrict__ fcos,
                           const float* __restrict__ fsin, bf16* __restrict__ qat,
                           bf16* __restrict__ kat, bf16* __restrict__ vT) {
  const int m = blockIdx.x;
  const int b = m >> 11, s = m & 2047;
  const int d = threadIdx.x;
  __shared__ float Aq[48]; __shared__ float Ak[2]; __shared__ float Av[2];
  const bf16* Prow = P + (size_t)m * NPAD;
  if (d < 48) Aq[d] = (float)Prow[d];
  else if (d < 50) Ak[d - 48] = (float)Prow[d];
  else if (d < 52) Av[d - 50] = (float)Prow[d];
  __syncthreads();
  const int dh = d & 127;
  const float co = fcos[s * 128 + dh], si = fsin[s * 128 + dh];
  const bool lo = (d < 128);
  float rq[6];
  #pragma unroll
  for (int r = 0; r < 6; ++r) {
    const bf16* Bq = Prow + 52 + r * 256;
    float x  = (float)Bq[d];
    float xp = (float)Bq[lo ? d + 128 : d - 128];
    rq[r] = lo ? (x * co - xp * si) : (xp * si + x * co);
  }
  #pragma unroll
  for (int h = 0; h < 8; ++h) {
    float a = 0.f;
    #pragma unroll
    for (int r = 0; r < 6; ++r) a += Aq[h * 6 + r] * rq[r];
    qat[((size_t)(b * 8 + h) * S_LEN + s) * DH + d] = (bf16)(a * QSCALE);
  }
  float ka = 0.f;
  #pragma unroll
  for (int r = 0; r < 2; ++r) {
    const bf16* Bk = Prow + 1588 + r * 256;
    float x  = (float)Bk[d];
    float xp = (float)Bk[lo ? d + 128 : d - 128];
    float rk = lo ? (x * co - xp * si) : (xp * si + x * co);
    ka += Ak[r] * rk;
  }
  kat[((size_t)b * S_LEN + s) * DH + d] = (bf16)(ka * 0.5f);
  float va = 0.f;
  #pragma unroll
  for (int r = 0; r < 2; ++r) va += Av[r] * (float)Prow[2100 + r * 256 + d];
  vT[((size_t)b * DH + d) * S_LEN + s] = (bf16)(va * 0.5f);
}

// ---------------------------------------------------------------- flash attention (R6 + diag-only mask)
// Fixed-max softmax (softcap bounds scores to +-50 => m=50 exactly):
// p = exp(-100*rcp(exp(0.04x)+1)).  8 waves/block: waves 0-3 take KV cols
// [0,32) of each 64-col step, waves 4-7 take [32,64); K/V staged once and
// shared.  Each block processes the uniform pair of q-tiles (31-p, p).
// Causal select executes only on the diagonal tile (wave-uniform branch).
__launch_bounds__(512)
__global__ void attn_kernel(const bf16* __restrict__ qat, const bf16* __restrict__ kat,
                            const bf16* __restrict__ vT, bf16* __restrict__ O) {
  const int pr = (int)blockIdx.x;                  // pair index 0..15
  const int bh = (int)blockIdx.y;
  const int b = bh >> 3, h8 = bh & 7;
  const int t = threadIdx.x, lane = t & 63, w = t >> 6;
  const int g = lane >> 4, c16 = lane & 15;
  const int rw = w & 3, hf = w >> 2;               // row-group, KV-half
  __shared__ __align__(16) bf16 Kb[2][64 * 256];   // 64 KB (also reused as Fc)
  __shared__ __align__(16) bf16 Vb[2][256 * 64];   // 64 KB
  __shared__ __align__(16) bf16 Pl[8][16 * 40];    // 10 KB per-wave P
  __shared__ f32x4 Lc[4][64];                      // 4 KB l-partials
  float* Fc = (float*)&Kb[0][0];                   // 64 KB f32 combine area

  const int ks_r = lane >> 5, ks_x = lane & 31;    // K stage: 2 rows/instr
  const int vs_r = lane >> 3, vs_x = lane & 7;     // V stage: 8 rows/instr
  const size_t kbase = (size_t)b * S_LEN * DH;
  const size_t vbase = (size_t)b * DH * S_LEN;

  auto stage = [&](int buf, int j0) {
    #pragma unroll
    for (int i = 0; i < 4; ++i) {                  // K tile 64x256, swz unit^(row&7)
      int lr = w * 8 + i * 2 + ks_r;
      int gx = ks_x ^ (lr & 7);
      gload16(kat + kbase + (size_t)(j0 + lr) * DH + gx * 8,
              &Kb[buf][(w * 8 + i * 2) * 256]);
    }
    #pragma unroll
    for (int i = 0; i < 4; ++i) {                  // V^T tile 256x64, swz unit^(row&7)
      int lr = w * 32 + i * 8 + vs_r;
      int gx = vs_x ^ (lr & 7);
      gload16(vT + vbase + (size_t)lr * S_LEN + j0 + gx * 8,
              &Vb[buf][(w * 32 + i * 8) * 64]);
    }
  };

  f32x4 z = {0.f, 0.f, 0.f, 0.f};
  const int kswz = c16 & 7;

  #pragma unroll 1
  for (int half = 0; half < 2; ++half) {
    const int qt = half ? pr : 31 - pr;            // heavy tile first
    const int q0 = qt * 64;
    const int rowg0 = q0 + rw * 16 + g * 4;

    bf16x8 qf[8];
    {
      const bf16* qrow = qat + ((size_t)bh * S_LEN + q0 + rw * 16 + c16) * DH;
      #pragma unroll
      for (int kf = 0; kf < 8; ++kf)
        qf[kf] = *reinterpret_cast<const bf16x8*>(qrow + kf * 32 + g * 8);
    }
    f32x4 accO[16];
    #pragma unroll
    for (int i = 0; i < 16; ++i) accO[i] = z;
    float lr4[4] = {0.f, 0.f, 0.f, 0.f};

    const int nst = qt + 1;                        // KVBLK=64 steps
    stage(0, 0);
    __syncthreads();

    for (int ts = 0; ts < nst; ++ts) {
      const int cb = ts & 1, nb = cb ^ 1;
      const int j0 = ts * 64;
      const bool fullTile = (ts + 1 < nst);        // strictly below diagonal
      if (fullTile) stage(nb, j0 + 64);            // async prefetch next tile

      f32x4 sc[2];
      #pragma unroll
      for (int nt = 0; nt < 2; ++nt) {             // QK^T: 16 rows x 32 cols (this half)
        f32x4 a = z;
        const int rk = hf * 32 + nt * 16 + c16;
        __builtin_amdgcn_s_setprio(1);
        #pragma unroll
        for (int kf = 0; kf < 8; ++kf) {
          bf16x8 kb = *reinterpret_cast<const bf16x8*>(
              &Kb[cb][rk * 256 + ((kf * 4 + g) ^ kswz) * 8]);
          a = __builtin_amdgcn_mfma_f32_16x16x32_bf16(qf[kf], kb, a, 0, 0, 0);
        }
        __builtin_amdgcn_s_setprio(0);
        sc[nt] = a;
      }
      // softcap + fixed-max exp -> P (bf16, wave-private LDS);
      // causal select only on the diagonal tile (wave-uniform branch)
      if (fullTile) {
        #pragma unroll
        for (int nt = 0; nt < 2; ++nt)
          #pragma unroll
          for (int r = 0; r < 4; ++r) {
            float x = sc[nt][r];
            float e2 = __expf(x * 0.04f);
            float p = __expf(-100.f * __frcp_rn(e2 + 1.f));
            lr4[r] += p;
            Pl[w][(g * 4 + r) * 40 + nt * 16 + c16] = (bf16)p;
          }
      } else {
        #pragma unroll
        for (int nt = 0; nt < 2; ++nt) {
          int col = j0 + hf * 32 + nt * 16 + c16;
          #pragma unroll
          for (int r = 0; r < 4; ++r) {
            float x = sc[nt][r];
            float e2 = __expf(x * 0.04f);
            float p = (col <= rowg0 + r)
                        ? __expf(-100.f * __frcp_rn(e2 + 1.f))
                        : 0.f;
            lr4[r] += p;
            Pl[w][(g * 4 + r) * 40 + nt * 16 + c16] = (bf16)p;
          }
        }
      }
      // PV: O[16x256] += P[16x32] @ V[32 cols of this half][256]
      bf16x8 pa = *reinterpret_cast<const bf16x8*>(&Pl[w][c16 * 40 + g * 8]);
      __builtin_amdgcn_s_setprio(1);
      #pragma unroll
      for (int dt = 0; dt < 16; ++dt) {
        int vrow = dt * 16 + c16;
        bf16x8 vb = *reinterpret_cast<const bf16x8*>(
            &Vb[cb][vrow * 64 + ((hf * 4 + g) ^ (vrow & 7)) * 8]);
        accO[dt] = __builtin_amdgcn_mfma_f32_16x16x32_bf16(pa, vb, accO[dt], 0, 0, 0);
      }
      __builtin_amdgcn_s_setprio(0);
      __syncthreads();                             // drains stage + read fences
    }

    // merge KV-halves: waves 4-7 dump partials, waves 0-3 add + write O
    if (hf == 1) {
      #pragma unroll
      for (int dt = 0; dt < 16; ++dt)
        #pragma unroll
        for (int r = 0; r < 4; ++r)
          Fc[rw * 4096 + (g * 4 + r) * 256 + dt * 16 + c16] = accO[dt][r];
      f32x4 lv = {lr4[0], lr4[1], lr4[2], lr4[3]};
      Lc[rw][lane] = lv;
    }
    __syncthreads();
    if (hf == 0) {
      f32x4 lo = Lc[rw][lane];
      #pragma unroll
      for (int r = 0; r < 4; ++r) lr4[r] += lo[r];
      #pragma unroll
      for (int dt = 0; dt < 16; ++dt)
        #pragma unroll
        for (int r = 0; r < 4; ++r)
          accO[dt][r] += Fc[rw * 4096 + (g * 4 + r) * 256 + dt * 16 + c16];
      #pragma unroll
      for (int r = 0; r < 4; ++r) {
        float l = lr4[r];
        l += __shfl_xor(l, 1);
        l += __shfl_xor(l, 2);
        l += __shfl_xor(l, 4);
        l += __shfl_xor(l, 8);
        float inv = 1.f / l;
        #pragma unroll
        for (int dt = 0; dt < 16; ++dt)
          O[((size_t)b * S_LEN + rowg0 + r) * (size_t)(NH * DH) + h8 * DH + dt * 16 + c16] =
              (bf16)(accO[dt][r] * inv);
      }
    }
    __syncthreads();                               // Fc free before next half's stage
  }
}

// ---------------------------------------------------------------- launch
extern "C" void kernel_launch(void* const* d_in, const int* in_sizes, int n_in,
                              void* d_out, int out_size, void* d_ws, size_t ws_size,
                              hipStream_t stream) {
  (void)in_sizes; (void)n_in; (void)out_size; (void)ws_size;
  const float* hs   = (const float*)d_in[0];
  const float* fcos = (const float*)d_in[1];
  const float* fsin = (const float*)d_in[2];
  // d_in[3] mask (analytic causal), d_in[4] kv_write_indices (arange) -- unused
  const float* Wq = (const float*)d_in[5];
  const float* Wk = (const float*)d_in[6];
  const float* Wv = (const float*)d_in[7];
  const float* Bq = (const float*)d_in[8];
  const float* Bk = (const float*)d_in[9];
  const float* Bv = (const float*)d_in[10];
  const float* Wo = (const float*)d_in[11];

  char* ws = (char*)d_ws;
  size_t off = 0;
  auto alloc = [&](size_t bytes) {
    void* p = ws + off;
    off += (bytes + 255) & ~(size_t)255;
    return p;
  };
  bf16*  Xbf  = (bf16*) alloc((size_t)MTOT * HIDN * 2);           // 16.8 MB
  bf16*  Wcat = (bf16*) alloc((size_t)NPAD * HIDN * 2);           // 11.0 MB
  bf16*  Wob  = (bf16*) alloc((size_t)HIDN * HIDN * 2);           //  8.4 MB
  bf16*  Pb   = (bf16*) alloc((size_t)MTOT * NPAD * 2);           // 22.0 MB
  bf16*  qat  = (bf16*) alloc((size_t)BATCH * NH * S_LEN * DH * 2); // 16.8 MB
  bf16*  kat  = (bf16*) alloc((size_t)BATCH * S_LEN * DH * 2);    //  2.1 MB
  bf16*  vT   = (bf16*) alloc((size_t)BATCH * DH * S_LEN * 2);    //  2.1 MB
  bf16*  Oat  = (bf16*) alloc((size_t)MTOT * NH * DH * 2);        // 16.8 MB
  float* out  = (float*)d_out;

  cast_all_kernel<<<dim3(4096 + NPAD + HIDN), dim3(256), 0, stream>>>(
      hs, Wq, Wk, Wv, Bq, Bk, Bv, Wo, Xbf, Wcat, Wob);
  gemm_bt8_kernel<bf16><<<dim3(NPAD / 128, MTOT / 128), dim3(512), 0, stream>>>(Xbf, Wcat, Pb, HIDN, NPAD);
  qkv_kernel<<<dim3(MTOT), dim3(256), 0, stream>>>(Pb, fcos, fsin, qat, kat, vT);
  attn_kernel<<<dim3(16, BATCH * NH), dim3(512), 0, stream>>>(qat, kat, vT, Oat);
  gemm_bt8_kernel<float><<<dim3(HIDN / 128, MTOT / 128), dim3(512), 0, stream>>>(Oat, Wob, out, HIDN, HIDN);
}